// Round 1
// baseline (1053.715 us; speedup 1.0000x reference)
//
#include <hip/hip_runtime.h>
#include <hip/hip_bf16.h>

#define NN 100000
#define EE 1600000
#define DD 128

typedef __attribute__((ext_vector_type(8))) short short8;
typedef __attribute__((ext_vector_type(4))) float f32x4;

// ---------------- dtype detection (int32 vs int64 edge_index) ----------------
__global__ void k_detect(const long long* __restrict__ ei64, int* __restrict__ flag) {
    __shared__ int ok;
    if (threadIdx.x == 0) ok = 1;
    __syncthreads();
    long long v = ei64[threadIdx.x];   // 256 samples; safe either way (2E elems)
    if (v < 0 || v >= (long long)NN) atomicAnd(&ok, 0);
    __syncthreads();
    if (threadIdx.x == 0) *flag = ok;  // 1 => int64 layout, 0 => int32
}

__device__ inline int load_edge(const int* ei32, const long long* ei64, int is64, size_t pos) {
    return is64 ? (int)ei64[pos] : ei32[pos];
}

// ---------------- counting sort: histogram -> scan -> fill ----------------
__global__ void k_hist(const int* __restrict__ ei32, const long long* __restrict__ ei64,
                       const int* __restrict__ flag, int* __restrict__ cnt) {
    int e = blockIdx.x * 256 + threadIdx.x;
    if (e >= EE) return;
    int is64 = *flag;
    int d = load_edge(ei32, ei64, is64, (size_t)EE + e);
    atomicAdd(&cnt[d], 1);
}

#define SCAN_T 1024
__global__ void k_scan(int* __restrict__ cnt /*in: counts, out: cursor*/,
                       int* __restrict__ rp) {
    __shared__ int sm[SCAN_T];
    int t = threadIdx.x;
    const int CH = (NN + SCAN_T - 1) / SCAN_T;   // 98
    int base = t * CH;
    int sum = 0;
    for (int i = 0; i < CH; ++i) {
        int idx = base + i;
        if (idx < NN) sum += cnt[idx];
    }
    sm[t] = sum;
    __syncthreads();
    // inclusive scan (Hillis-Steele)
    for (int off = 1; off < SCAN_T; off <<= 1) {
        int v = (t >= off) ? sm[t - off] : 0;
        __syncthreads();
        sm[t] += v;
        __syncthreads();
    }
    int running = sm[t] - sum;  // exclusive
    for (int i = 0; i < CH; ++i) {
        int idx = base + i;
        if (idx < NN) {
            int c = cnt[idx];
            rp[idx] = running;
            cnt[idx] = running;   // cursor for fill
            running += c;
        }
    }
    if (t == 0) rp[NN] = EE;
}

__global__ void k_fill(const int* __restrict__ ei32, const long long* __restrict__ ei64,
                       const int* __restrict__ flag, int* __restrict__ cursor,
                       int* __restrict__ ssrc) {
    int e = blockIdx.x * 256 + threadIdx.x;
    if (e >= EE) return;
    int is64 = *flag;
    int s = load_edge(ei32, ei64, is64, (size_t)e);
    int d = load_edge(ei32, ei64, is64, (size_t)EE + e);
    int pos = atomicAdd(&cursor[d], 1);
    ssrc[pos] = s;
}

// ---------------- weight split: f32 -> bf16 hi + bf16 lo ----------------
__device__ inline void split1(float x, short& h, short& l) {
    unsigned b = __float_as_uint(x);
    h = (short)(b >> 16);                       // truncated hi
    float hf = __uint_as_float(b & 0xFFFF0000u);
    float r = x - hf;                           // exact residual
    l = (short)(__float_as_uint(r) >> 16);
}

__global__ void k_prepw(const float* __restrict__ w0, const float* __restrict__ w1,
                        const float* __restrict__ w2, const float* __restrict__ w3,
                        const float* __restrict__ w4, const float* __restrict__ w5,
                        short* __restrict__ whi, short* __restrict__ wlo) {
    int i = blockIdx.x * 256 + threadIdx.x;     // 6 * 16384
    if (i >= 6 * 16384) return;
    int slot = i >> 14, idx = i & 16383;
    const float* w = slot == 0 ? w0 : slot == 1 ? w1 : slot == 2 ? w2
                   : slot == 3 ? w3 : slot == 4 ? w4 : w5;
    short h, l;
    split1(w[idx], h, l);
    whi[i] = h;
    wlo[i] = l;
}

// ---------------- GEMM: out = relu(A@Wa.T [+ A2@Wb.T] + bias) ----------------
// A row-major [N,128] f32; W as split bf16 hi/lo row-major [128,128].
// Wave computes 32 rows x 128 cols via 16x16x32 bf16 MFMA; block = 4 waves = 128 rows.
__device__ inline void gemm_pass(const float* __restrict__ A,
                                 const short* __restrict__ Wh,
                                 const short* __restrict__ Wl,
                                 int rowBase, int lr, int lk, f32x4 acc[2][8]) {
#pragma unroll
    for (int ks = 0; ks < 4; ++ks) {
        int kf = ks * 32 + lk * 8;
        short8 bh[8], bl[8];
#pragma unroll
        for (int nt = 0; nt < 8; ++nt) {
            int n = nt * 16 + lr;
            bh[nt] = *(const short8*)(Wh + n * 128 + kf);
            bl[nt] = *(const short8*)(Wl + n * 128 + kf);
        }
#pragma unroll
        for (int mt = 0; mt < 2; ++mt) {
            int row = rowBase + mt * 16 + lr;
            int rc = row < NN ? row : NN - 1;
            const float* ap = A + (size_t)rc * 128 + kf;
            float4 a0 = *(const float4*)ap;
            float4 a1 = *(const float4*)(ap + 4);
            float av[8] = {a0.x, a0.y, a0.z, a0.w, a1.x, a1.y, a1.z, a1.w};
            short8 ah, al;
#pragma unroll
            for (int j = 0; j < 8; ++j) {
                short h, l;
                split1(av[j], h, l);
                ah[j] = h;
                al[j] = l;
            }
#pragma unroll
            for (int nt = 0; nt < 8; ++nt) {
                acc[mt][nt] = __builtin_amdgcn_mfma_f32_16x16x32_bf16(ah, bh[nt], acc[mt][nt], 0, 0, 0);
                acc[mt][nt] = __builtin_amdgcn_mfma_f32_16x16x32_bf16(ah, bl[nt], acc[mt][nt], 0, 0, 0);
                acc[mt][nt] = __builtin_amdgcn_mfma_f32_16x16x32_bf16(al, bh[nt], acc[mt][nt], 0, 0, 0);
            }
        }
    }
}

template <bool DUAL>
__global__ __launch_bounds__(256) void k_gemm(const float* __restrict__ A,
                                              const short* __restrict__ Wh,
                                              const short* __restrict__ Wl,
                                              const float* __restrict__ A2,
                                              const short* __restrict__ Wh2,
                                              const short* __restrict__ Wl2,
                                              const float* __restrict__ bias,
                                              float* __restrict__ out) {
    int wave = threadIdx.x >> 6;
    int lane = threadIdx.x & 63;
    int lr = lane & 15;
    int lk = lane >> 4;
    int rowBase = blockIdx.x * 128 + wave * 32;

    f32x4 acc[2][8];
#pragma unroll
    for (int mt = 0; mt < 2; ++mt)
#pragma unroll
        for (int nt = 0; nt < 8; ++nt) acc[mt][nt] = (f32x4){0.f, 0.f, 0.f, 0.f};

    gemm_pass(A, Wh, Wl, rowBase, lr, lk, acc);
    if (DUAL) gemm_pass(A2, Wh2, Wl2, rowBase, lr, lk, acc);

    // epilogue: C/D layout col=lane&15, row=(lane>>4)*4+reg  [verified mapping]
#pragma unroll
    for (int mt = 0; mt < 2; ++mt) {
#pragma unroll
        for (int nt = 0; nt < 8; ++nt) {
            int col = nt * 16 + lr;
            float b = bias[col];
#pragma unroll
            for (int r = 0; r < 4; ++r) {
                int row = rowBase + mt * 16 + lk * 4 + r;
                if (row < NN) {
                    float v = acc[mt][nt][r] + b;
                    out[(size_t)row * 128 + col] = v > 0.f ? v : 0.f;
                }
            }
        }
    }
}

// ---------------- mean aggregation over CSR: wave per node ----------------
__global__ __launch_bounds__(256) void k_agg(const float* __restrict__ h,
                                             const int* __restrict__ rp,
                                             const int* __restrict__ ssrc,
                                             float* __restrict__ out) {
    int wid = (int)((blockIdx.x * 256 + threadIdx.x) >> 6);
    int lane = threadIdx.x & 63;
    if (wid >= NN) return;
    int s = __builtin_amdgcn_readfirstlane(rp[wid]);
    int e = __builtin_amdgcn_readfirstlane(rp[wid + 1]);
    const float2* hp = (const float2*)h;
    float ax = 0.f, ay = 0.f;
    int i = s;
    for (; i + 4 <= e; i += 4) {
        int s0 = ssrc[i], s1 = ssrc[i + 1], s2 = ssrc[i + 2], s3 = ssrc[i + 3];
        float2 v0 = hp[(size_t)s0 * 64 + lane];
        float2 v1 = hp[(size_t)s1 * 64 + lane];
        float2 v2 = hp[(size_t)s2 * 64 + lane];
        float2 v3 = hp[(size_t)s3 * 64 + lane];
        ax += v0.x + v1.x + v2.x + v3.x;
        ay += v0.y + v1.y + v2.y + v3.y;
    }
    for (; i < e; ++i) {
        int s0 = ssrc[i];
        float2 v0 = hp[(size_t)s0 * 64 + lane];
        ax += v0.x;
        ay += v0.y;
    }
    int deg = e - s;
    float inv = deg > 0 ? 1.0f / (float)deg : 0.f;
    float2 o;
    o.x = ax * inv;
    o.y = ay * inv;
    ((float2*)out)[(size_t)wid * 64 + lane] = o;
}

// ---------------- launch ----------------
extern "C" void kernel_launch(void* const* d_in, const int* in_sizes, int n_in,
                              void* d_out, int out_size, void* d_ws, size_t ws_size,
                              hipStream_t stream) {
    const float* x = (const float*)d_in[0];
    const int* ei32 = (const int*)d_in[1];
    const long long* ei64 = (const long long*)d_in[1];
    const float* b1 = (const float*)d_in[3];
    const float* b2 = (const float*)d_in[5];
    const float* c1_bl = (const float*)d_in[7];
    const float* c2_bl = (const float*)d_in[10];
    float* out = (float*)d_out;

    char* ws = (char*)d_ws;
    const size_t HBYTES = (size_t)NN * 128 * 4;  // 51,200,000
    float* hA = (float*)ws;
    float* agg = (float*)(ws + HBYTES);
    int* ssrc = (int*)(ws + 2 * HBYTES);                    // E ints
    int* rp = (int*)(ws + 2 * HBYTES + 6400000);            // N+1 ints (padded 400128)
    int* cursor = (int*)(ws + 2 * HBYTES + 6400000 + 400128);
    short* whi = (short*)(ws + 2 * HBYTES + 6400000 + 2 * 400128);
    short* wlo = whi + 6 * 16384;
    int* flag = (int*)((char*)(wlo + 6 * 16384));

    k_detect<<<1, 256, 0, stream>>>(ei64, flag);
    hipMemsetAsync(cursor, 0, (size_t)NN * 4, stream);
    int egrid = (EE + 255) / 256;
    k_hist<<<egrid, 256, 0, stream>>>(ei32, ei64, flag, cursor);
    k_scan<<<1, SCAN_T, 0, stream>>>(cursor, rp);
    k_fill<<<egrid, 256, 0, stream>>>(ei32, ei64, flag, cursor, ssrc);
    k_prepw<<<(6 * 16384 + 255) / 256, 256, 0, stream>>>(
        (const float*)d_in[2], (const float*)d_in[6], (const float*)d_in[8],
        (const float*)d_in[4], (const float*)d_in[9], (const float*)d_in[11], whi, wlo);

    dim3 g((NN + 127) / 128);
    int agrid = (NN + 3) / 4;
    // h1 = relu(x@W1.T+b1)
    k_gemm<false><<<g, 256, 0, stream>>>(x, whi + 0 * 16384, wlo + 0 * 16384,
                                         nullptr, nullptr, nullptr, b1, hA);
    // conv1
    k_agg<<<agrid, 256, 0, stream>>>(hA, rp, ssrc, agg);
    k_gemm<true><<<g, 256, 0, stream>>>(agg, whi + 1 * 16384, wlo + 1 * 16384,
                                        hA, whi + 2 * 16384, wlo + 2 * 16384, c1_bl, out);
    // h3 = relu(h2@W2.T+b2)
    k_gemm<false><<<g, 256, 0, stream>>>(out, whi + 3 * 16384, wlo + 3 * 16384,
                                         nullptr, nullptr, nullptr, b2, hA);
    // conv2
    k_agg<<<agrid, 256, 0, stream>>>(hA, rp, ssrc, agg);
    k_gemm<true><<<g, 256, 0, stream>>>(agg, whi + 4 * 16384, wlo + 4 * 16384,
                                        hA, whi + 5 * 16384, wlo + 5 * 16384, c2_bl, out);
}

// Round 2
// 785.692 us; speedup vs baseline: 1.3411x; 1.3411x over previous
//
#include <hip/hip_runtime.h>
#include <hip/hip_bf16.h>

#define NN 100000
#define EE 1600000
#define DD 128

typedef __attribute__((ext_vector_type(8))) short short8;
typedef __attribute__((ext_vector_type(4))) float f32x4;

// ---------------- dtype detection (int32 vs int64 edge_index) ----------------
__global__ void k_detect(const long long* __restrict__ ei64, int* __restrict__ flag) {
    __shared__ int ok;
    if (threadIdx.x == 0) ok = 1;
    __syncthreads();
    long long v = ei64[threadIdx.x];   // 256 samples; safe either way (2E elems)
    if (v < 0 || v >= (long long)NN) atomicAnd(&ok, 0);
    __syncthreads();
    if (threadIdx.x == 0) *flag = ok;  // 1 => int64 layout, 0 => int32
}

__device__ inline int load_edge(const int* ei32, const long long* ei64, int is64, size_t pos) {
    return is64 ? (int)ei64[pos] : ei32[pos];
}

// ---------------- counting sort: histogram -> scan -> fill ----------------
__global__ void k_hist(const int* __restrict__ ei32, const long long* __restrict__ ei64,
                       const int* __restrict__ flag, int* __restrict__ cnt) {
    int e = blockIdx.x * 256 + threadIdx.x;
    if (e >= EE) return;
    int is64 = *flag;
    int d = load_edge(ei32, ei64, is64, (size_t)EE + e);
    atomicAdd(&cnt[d], 1);
}

// ---- hierarchical exclusive scan over NN counts: A (block partials), B (scan
// block sums), C (add offsets, write rp + cursor). Total ~1.2 MB traffic. ----
#define SCB 1024
#define NB ((NN + SCB - 1) / SCB)   // 98

__global__ __launch_bounds__(SCB) void k_scanA(const int* __restrict__ cnt,
                                               int* __restrict__ excl,
                                               int* __restrict__ bsum) {
    __shared__ int sm[SCB];
    int t = threadIdx.x;
    int g = blockIdx.x * SCB + t;
    int v = (g < NN) ? cnt[g] : 0;
    sm[t] = v;
    __syncthreads();
    for (int off = 1; off < SCB; off <<= 1) {
        int u = (t >= off) ? sm[t - off] : 0;
        __syncthreads();
        sm[t] += u;
        __syncthreads();
    }
    if (g < NN) excl[g] = sm[t] - v;
    if (t == SCB - 1) bsum[blockIdx.x] = sm[t];
}

__global__ __launch_bounds__(128) void k_scanB(int* __restrict__ bsum) {
    __shared__ int sm[128];
    int t = threadIdx.x;
    int v = (t < NB) ? bsum[t] : 0;
    sm[t] = v;
    __syncthreads();
    for (int off = 1; off < 128; off <<= 1) {
        int u = (t >= off) ? sm[t - off] : 0;
        __syncthreads();
        sm[t] += u;
        __syncthreads();
    }
    if (t < NB) bsum[t] = sm[t] - v;   // exclusive block offsets
}

__global__ __launch_bounds__(SCB) void k_scanC(const int* __restrict__ excl,
                                               const int* __restrict__ bsum,
                                               int* __restrict__ rp,
                                               int* __restrict__ cursor) {
    int g = blockIdx.x * SCB + threadIdx.x;
    if (g < NN) {
        int v = excl[g] + bsum[blockIdx.x];
        rp[g] = v;
        cursor[g] = v;
    }
    if (blockIdx.x == 0 && threadIdx.x == 0) rp[NN] = EE;
}

__global__ void k_fill(const int* __restrict__ ei32, const long long* __restrict__ ei64,
                       const int* __restrict__ flag, int* __restrict__ cursor,
                       int* __restrict__ ssrc) {
    int e = blockIdx.x * 256 + threadIdx.x;
    if (e >= EE) return;
    int is64 = *flag;
    int s = load_edge(ei32, ei64, is64, (size_t)e);
    int d = load_edge(ei32, ei64, is64, (size_t)EE + e);
    int pos = atomicAdd(&cursor[d], 1);
    ssrc[pos] = s;
}

// ---------------- weight split: f32 -> bf16 hi + bf16 lo ----------------
__device__ inline void split1(float x, short& h, short& l) {
    unsigned b = __float_as_uint(x);
    h = (short)(b >> 16);                       // truncated hi
    float hf = __uint_as_float(b & 0xFFFF0000u);
    float r = x - hf;                           // exact residual
    l = (short)(__float_as_uint(r) >> 16);
}

__global__ void k_prepw(const float* __restrict__ w0, const float* __restrict__ w1,
                        const float* __restrict__ w2, const float* __restrict__ w3,
                        const float* __restrict__ w4, const float* __restrict__ w5,
                        short* __restrict__ whi, short* __restrict__ wlo) {
    int i = blockIdx.x * 256 + threadIdx.x;     // 6 * 16384
    if (i >= 6 * 16384) return;
    int slot = i >> 14, idx = i & 16383;
    const float* w = slot == 0 ? w0 : slot == 1 ? w1 : slot == 2 ? w2
                   : slot == 3 ? w3 : slot == 4 ? w4 : w5;
    short h, l;
    split1(w[idx], h, l);
    whi[i] = h;
    wlo[i] = l;
}

// ---------------- GEMM: out = relu(A@Wa.T [+ A2@Wb.T] + bias) ----------------
// A row-major [N,128] f32; W as split bf16 hi/lo row-major [128,128].
// Wave computes 32 rows x 128 cols via 16x16x32 bf16 MFMA; block = 4 waves = 128 rows.
__device__ inline void gemm_pass(const float* __restrict__ A,
                                 const short* __restrict__ Wh,
                                 const short* __restrict__ Wl,
                                 int rowBase, int lr, int lk, f32x4 acc[2][8]) {
#pragma unroll
    for (int ks = 0; ks < 4; ++ks) {
        int kf = ks * 32 + lk * 8;
        short8 bh[8], bl[8];
#pragma unroll
        for (int nt = 0; nt < 8; ++nt) {
            int n = nt * 16 + lr;
            bh[nt] = *(const short8*)(Wh + n * 128 + kf);
            bl[nt] = *(const short8*)(Wl + n * 128 + kf);
        }
#pragma unroll
        for (int mt = 0; mt < 2; ++mt) {
            int row = rowBase + mt * 16 + lr;
            int rc = row < NN ? row : NN - 1;
            const float* ap = A + (size_t)rc * 128 + kf;
            float4 a0 = *(const float4*)ap;
            float4 a1 = *(const float4*)(ap + 4);
            float av[8] = {a0.x, a0.y, a0.z, a0.w, a1.x, a1.y, a1.z, a1.w};
            short8 ah, al;
#pragma unroll
            for (int j = 0; j < 8; ++j) {
                short h, l;
                split1(av[j], h, l);
                ah[j] = h;
                al[j] = l;
            }
#pragma unroll
            for (int nt = 0; nt < 8; ++nt) {
                acc[mt][nt] = __builtin_amdgcn_mfma_f32_16x16x32_bf16(ah, bh[nt], acc[mt][nt], 0, 0, 0);
                acc[mt][nt] = __builtin_amdgcn_mfma_f32_16x16x32_bf16(ah, bl[nt], acc[mt][nt], 0, 0, 0);
                acc[mt][nt] = __builtin_amdgcn_mfma_f32_16x16x32_bf16(al, bh[nt], acc[mt][nt], 0, 0, 0);
            }
        }
    }
}

template <bool DUAL>
__global__ __launch_bounds__(256) void k_gemm(const float* __restrict__ A,
                                              const short* __restrict__ Wh,
                                              const short* __restrict__ Wl,
                                              const float* __restrict__ A2,
                                              const short* __restrict__ Wh2,
                                              const short* __restrict__ Wl2,
                                              const float* __restrict__ bias,
                                              float* __restrict__ out) {
    int wave = threadIdx.x >> 6;
    int lane = threadIdx.x & 63;
    int lr = lane & 15;
    int lk = lane >> 4;
    int rowBase = blockIdx.x * 128 + wave * 32;

    f32x4 acc[2][8];
#pragma unroll
    for (int mt = 0; mt < 2; ++mt)
#pragma unroll
        for (int nt = 0; nt < 8; ++nt) acc[mt][nt] = (f32x4){0.f, 0.f, 0.f, 0.f};

    gemm_pass(A, Wh, Wl, rowBase, lr, lk, acc);
    if (DUAL) gemm_pass(A2, Wh2, Wl2, rowBase, lr, lk, acc);

    // epilogue: C/D layout col=lane&15, row=(lane>>4)*4+reg  [verified mapping]
#pragma unroll
    for (int mt = 0; mt < 2; ++mt) {
#pragma unroll
        for (int nt = 0; nt < 8; ++nt) {
            int col = nt * 16 + lr;
            float b = bias[col];
#pragma unroll
            for (int r = 0; r < 4; ++r) {
                int row = rowBase + mt * 16 + lk * 4 + r;
                if (row < NN) {
                    float v = acc[mt][nt][r] + b;
                    out[(size_t)row * 128 + col] = v > 0.f ? v : 0.f;
                }
            }
        }
    }
}

// ---------------- mean aggregation over CSR: wave per node ----------------
__global__ __launch_bounds__(256) void k_agg(const float* __restrict__ h,
                                             const int* __restrict__ rp,
                                             const int* __restrict__ ssrc,
                                             float* __restrict__ out) {
    int wid = (int)((blockIdx.x * 256 + threadIdx.x) >> 6);
    int lane = threadIdx.x & 63;
    if (wid >= NN) return;
    int s = __builtin_amdgcn_readfirstlane(rp[wid]);
    int e = __builtin_amdgcn_readfirstlane(rp[wid + 1]);
    const float2* hp = (const float2*)h;
    float ax = 0.f, ay = 0.f;
    int i = s;
    for (; i + 4 <= e; i += 4) {
        int s0 = ssrc[i], s1 = ssrc[i + 1], s2 = ssrc[i + 2], s3 = ssrc[i + 3];
        float2 v0 = hp[(size_t)s0 * 64 + lane];
        float2 v1 = hp[(size_t)s1 * 64 + lane];
        float2 v2 = hp[(size_t)s2 * 64 + lane];
        float2 v3 = hp[(size_t)s3 * 64 + lane];
        ax += v0.x + v1.x + v2.x + v3.x;
        ay += v0.y + v1.y + v2.y + v3.y;
    }
    for (; i < e; ++i) {
        int s0 = ssrc[i];
        float2 v0 = hp[(size_t)s0 * 64 + lane];
        ax += v0.x;
        ay += v0.y;
    }
    int deg = e - s;
    float inv = deg > 0 ? 1.0f / (float)deg : 0.f;
    float2 o;
    o.x = ax * inv;
    o.y = ay * inv;
    ((float2*)out)[(size_t)wid * 64 + lane] = o;
}

// ---------------- launch ----------------
extern "C" void kernel_launch(void* const* d_in, const int* in_sizes, int n_in,
                              void* d_out, int out_size, void* d_ws, size_t ws_size,
                              hipStream_t stream) {
    const float* x = (const float*)d_in[0];
    const int* ei32 = (const int*)d_in[1];
    const long long* ei64 = (const long long*)d_in[1];
    const float* b1 = (const float*)d_in[3];
    const float* b2 = (const float*)d_in[5];
    const float* c1_bl = (const float*)d_in[7];
    const float* c2_bl = (const float*)d_in[10];
    float* out = (float*)d_out;

    char* ws = (char*)d_ws;
    const size_t HBYTES = (size_t)NN * 128 * 4;  // 51,200,000
    float* hA = (float*)ws;
    float* agg = (float*)(ws + HBYTES);
    int* ssrc = (int*)(ws + 2 * HBYTES);                    // E ints
    int* rp = (int*)(ws + 2 * HBYTES + 6400000);            // N+1 ints (padded 400128)
    int* cursor = (int*)(ws + 2 * HBYTES + 6400000 + 400128);
    short* whi = (short*)(ws + 2 * HBYTES + 6400000 + 2 * 400128);
    short* wlo = whi + 6 * 16384;
    int* flag = (int*)((char*)(wlo + 6 * 16384));

    // scan temporaries alias later-written buffers (stream is in-order):
    int* cnt = (int*)hA;           // histogram counts (hA written only later)
    int* excl = (int*)agg;         // block-local exclusive partials
    int* bsum = ((int*)agg) + 128 * 1024;  // 98 block sums

    k_detect<<<1, 256, 0, stream>>>(ei64, flag);
    hipMemsetAsync(cnt, 0, (size_t)NN * 4, stream);
    int egrid = (EE + 255) / 256;
    k_hist<<<egrid, 256, 0, stream>>>(ei32, ei64, flag, cnt);
    k_scanA<<<NB, SCB, 0, stream>>>(cnt, excl, bsum);
    k_scanB<<<1, 128, 0, stream>>>(bsum);
    k_scanC<<<NB, SCB, 0, stream>>>(excl, bsum, rp, cursor);
    k_fill<<<egrid, 256, 0, stream>>>(ei32, ei64, flag, cursor, ssrc);
    k_prepw<<<(6 * 16384 + 255) / 256, 256, 0, stream>>>(
        (const float*)d_in[2], (const float*)d_in[6], (const float*)d_in[8],
        (const float*)d_in[4], (const float*)d_in[9], (const float*)d_in[11], whi, wlo);

    dim3 g((NN + 127) / 128);
    int agrid = (NN + 3) / 4;
    // h1 = relu(x@W1.T+b1)
    k_gemm<false><<<g, 256, 0, stream>>>(x, whi + 0 * 16384, wlo + 0 * 16384,
                                         nullptr, nullptr, nullptr, b1, hA);
    // conv1
    k_agg<<<agrid, 256, 0, stream>>>(hA, rp, ssrc, agg);
    k_gemm<true><<<g, 256, 0, stream>>>(agg, whi + 1 * 16384, wlo + 1 * 16384,
                                        hA, whi + 2 * 16384, wlo + 2 * 16384, c1_bl, out);
    // h3 = relu(h2@W2.T+b2)
    k_gemm<false><<<g, 256, 0, stream>>>(out, whi + 3 * 16384, wlo + 3 * 16384,
                                         nullptr, nullptr, nullptr, b2, hA);
    // conv2
    k_agg<<<agrid, 256, 0, stream>>>(hA, rp, ssrc, agg);
    k_gemm<true><<<g, 256, 0, stream>>>(agg, whi + 4 * 16384, wlo + 4 * 16384,
                                        hA, whi + 5 * 16384, wlo + 5 * 16384, c2_bl, out);
}

// Round 3
// 650.258 us; speedup vs baseline: 1.6205x; 1.2083x over previous
//
#include <hip/hip_runtime.h>
#include <hip/hip_bf16.h>

#define NN 100000
#define EE 1600000
#define DD 128

#define BSH 9                       // 512 nodes per bucket
#define NBUK ((NN + 511) / 512)     // 196
#define EPB 8192                    // edges per block in partition kernels

typedef __attribute__((ext_vector_type(8))) short short8;
typedef __attribute__((ext_vector_type(4))) float f32x4;

// ---------------- dtype detection (int32 vs int64 edge_index) ----------------
__global__ void k_detect(const long long* __restrict__ ei64, int* __restrict__ flag) {
    __shared__ int ok;
    if (threadIdx.x == 0) ok = 1;
    __syncthreads();
    long long v = ei64[threadIdx.x];   // 256 samples; safe either way (2E elems)
    if (v < 0 || v >= (long long)NN) atomicAnd(&ok, 0);
    __syncthreads();
    if (threadIdx.x == 0) *flag = ok;  // 1 => int64 layout, 0 => int32
}

__device__ inline int load_edge(const int* ei32, const long long* ei64, int is64, size_t pos) {
    return is64 ? (int)ei64[pos] : ei32[pos];
}

// ---------------- bucket histogram (196 buckets of 512 dst nodes) ----------------
__global__ __launch_bounds__(1024) void k_bhist(const int* __restrict__ ei32,
                                                const long long* __restrict__ ei64,
                                                const int* __restrict__ flag,
                                                int* __restrict__ bcnt) {
    __shared__ int h[NBUK];
    int t = threadIdx.x;
    if (t < NBUK) h[t] = 0;
    __syncthreads();
    int is64 = *flag;
    int base = blockIdx.x * EPB;
    int end = min(base + EPB, EE);
    for (int e = base + t; e < end; e += 1024) {
        int d = load_edge(ei32, ei64, is64, (size_t)EE + e);
        atomicAdd(&h[d >> BSH], 1);
    }
    __syncthreads();
    if (t < NBUK && h[t] > 0) atomicAdd(&bcnt[t], h[t]);
}

__global__ __launch_bounds__(256) void k_bscan(const int* __restrict__ bcnt,
                                               int* __restrict__ bbase,
                                               int* __restrict__ bcur) {
    __shared__ int sm[256];
    int t = threadIdx.x;
    int v = (t < NBUK) ? bcnt[t] : 0;
    sm[t] = v;
    __syncthreads();
    for (int off = 1; off < 256; off <<= 1) {
        int u = (t >= off) ? sm[t - off] : 0;
        __syncthreads();
        sm[t] += u;
        __syncthreads();
    }
    if (t < NBUK) {
        int b = sm[t] - v;
        bbase[t] = b;
        bcur[t] = b;
    }
    if (t == 0) bbase[NBUK] = EE;
}

// ---------------- partition edges into bucket-contiguous staging ----------------
// staged value: src (17 bits) | dstLocal (9 bits) << 17
__global__ __launch_bounds__(1024) void k_part(const int* __restrict__ ei32,
                                               const long long* __restrict__ ei64,
                                               const int* __restrict__ flag,
                                               int* __restrict__ bcur,
                                               unsigned* __restrict__ eb) {
    __shared__ int h[NBUK];
    __shared__ int cbase[NBUK];
    int t = threadIdx.x;
    if (t < NBUK) h[t] = 0;
    __syncthreads();
    int is64 = *flag;
    int base = blockIdx.x * EPB;
    int end = min(base + EPB, EE);
    int mys[8], myd[8];
    int cnt_i = 0;
    for (int e = base + t; e < end; e += 1024) {
        int s = load_edge(ei32, ei64, is64, (size_t)e);
        int d = load_edge(ei32, ei64, is64, (size_t)EE + e);
        mys[cnt_i] = s;
        myd[cnt_i] = d;
        ++cnt_i;
        atomicAdd(&h[d >> BSH], 1);
    }
    __syncthreads();
    if (t < NBUK && h[t] > 0) cbase[t] = atomicAdd(&bcur[t], h[t]);
    __syncthreads();
    if (t < NBUK) h[t] = 0;   // reuse as local cursor
    __syncthreads();
    for (int i = 0; i < cnt_i; ++i) {
        int b = myd[i] >> BSH;
        int slot = atomicAdd(&h[b], 1);
        unsigned v = (unsigned)mys[i] | ((unsigned)(myd[i] & 511) << 17);
        eb[cbase[b] + slot] = v;
    }
}

// ---------------- per-bucket counting sort: one block per bucket ----------------
__global__ __launch_bounds__(1024) void k_bucket(const unsigned* __restrict__ eb,
                                                 const int* __restrict__ bbase,
                                                 int* __restrict__ rp,
                                                 int* __restrict__ ssrc) {
    __shared__ int ncnt[512];
    __shared__ int cur[512];
    int b = blockIdx.x, t = threadIdx.x;
    int ebeg = bbase[b], eend = bbase[b + 1];
    int nodeBase = b << BSH;
    int nNodes = min(512, NN - nodeBase);
    if (t < 512) ncnt[t] = 0;
    __syncthreads();
    for (int i = ebeg + t; i < eend; i += 1024) {
        unsigned v = eb[i];
        atomicAdd(&ncnt[v >> 17], 1);
    }
    __syncthreads();
    int own = (t < 512) ? ncnt[t] : 0;
    for (int off = 1; off < 512; off <<= 1) {
        int u = (t >= off && t < 512) ? ncnt[t - off] : 0;
        __syncthreads();
        if (t < 512) ncnt[t] += u;
        __syncthreads();
    }
    if (t < 512) {
        int excl = ncnt[t] - own;
        cur[t] = ebeg + excl;
        if (t < nNodes) rp[nodeBase + t] = ebeg + excl;
    }
    __syncthreads();
    for (int i = ebeg + t; i < eend; i += 1024) {
        unsigned v = eb[i];
        int slot = atomicAdd(&cur[v >> 17], 1);
        ssrc[slot] = (int)(v & 0x1FFFFu);
    }
    if (b == 0 && t == 0) rp[NN] = EE;
}

// ---------------- weight split: f32 -> bf16 hi + bf16 lo ----------------
__device__ inline void split1(float x, short& h, short& l) {
    unsigned b = __float_as_uint(x);
    h = (short)(b >> 16);                       // truncated hi
    float hf = __uint_as_float(b & 0xFFFF0000u);
    float r = x - hf;                           // exact residual
    l = (short)(__float_as_uint(r) >> 16);
}

__global__ void k_prepw(const float* __restrict__ w0, const float* __restrict__ w1,
                        const float* __restrict__ w2, const float* __restrict__ w3,
                        const float* __restrict__ w4, const float* __restrict__ w5,
                        short* __restrict__ whi, short* __restrict__ wlo) {
    int i = blockIdx.x * 256 + threadIdx.x;     // 6 * 16384
    if (i >= 6 * 16384) return;
    int slot = i >> 14, idx = i & 16383;
    const float* w = slot == 0 ? w0 : slot == 1 ? w1 : slot == 2 ? w2
                   : slot == 3 ? w3 : slot == 4 ? w4 : w5;
    short h, l;
    split1(w[idx], h, l);
    whi[i] = h;
    wlo[i] = l;
}

// ---------------- GEMM: out = relu(A@Wa.T [+ A2@Wb.T] + bias) ----------------
// A row-major [N,128] f32; W as split bf16 hi/lo row-major [128,128].
// Wave computes 32 rows x 128 cols via 16x16x32 bf16 MFMA; block = 4 waves = 128 rows.
__device__ inline void gemm_pass(const float* __restrict__ A,
                                 const short* __restrict__ Wh,
                                 const short* __restrict__ Wl,
                                 int rowBase, int lr, int lk, f32x4 acc[2][8]) {
#pragma unroll
    for (int ks = 0; ks < 4; ++ks) {
        int kf = ks * 32 + lk * 8;
        short8 bh[8], bl[8];
#pragma unroll
        for (int nt = 0; nt < 8; ++nt) {
            int n = nt * 16 + lr;
            bh[nt] = *(const short8*)(Wh + n * 128 + kf);
            bl[nt] = *(const short8*)(Wl + n * 128 + kf);
        }
#pragma unroll
        for (int mt = 0; mt < 2; ++mt) {
            int row = rowBase + mt * 16 + lr;
            int rc = row < NN ? row : NN - 1;
            const float* ap = A + (size_t)rc * 128 + kf;
            float4 a0 = *(const float4*)ap;
            float4 a1 = *(const float4*)(ap + 4);
            float av[8] = {a0.x, a0.y, a0.z, a0.w, a1.x, a1.y, a1.z, a1.w};
            short8 ah, al;
#pragma unroll
            for (int j = 0; j < 8; ++j) {
                short h, l;
                split1(av[j], h, l);
                ah[j] = h;
                al[j] = l;
            }
#pragma unroll
            for (int nt = 0; nt < 8; ++nt) {
                acc[mt][nt] = __builtin_amdgcn_mfma_f32_16x16x32_bf16(ah, bh[nt], acc[mt][nt], 0, 0, 0);
                acc[mt][nt] = __builtin_amdgcn_mfma_f32_16x16x32_bf16(ah, bl[nt], acc[mt][nt], 0, 0, 0);
                acc[mt][nt] = __builtin_amdgcn_mfma_f32_16x16x32_bf16(al, bh[nt], acc[mt][nt], 0, 0, 0);
            }
        }
    }
}

template <bool DUAL>
__global__ __launch_bounds__(256) void k_gemm(const float* __restrict__ A,
                                              const short* __restrict__ Wh,
                                              const short* __restrict__ Wl,
                                              const float* __restrict__ A2,
                                              const short* __restrict__ Wh2,
                                              const short* __restrict__ Wl2,
                                              const float* __restrict__ bias,
                                              float* __restrict__ out) {
    int wave = threadIdx.x >> 6;
    int lane = threadIdx.x & 63;
    int lr = lane & 15;
    int lk = lane >> 4;
    int rowBase = blockIdx.x * 128 + wave * 32;

    f32x4 acc[2][8];
#pragma unroll
    for (int mt = 0; mt < 2; ++mt)
#pragma unroll
        for (int nt = 0; nt < 8; ++nt) acc[mt][nt] = (f32x4){0.f, 0.f, 0.f, 0.f};

    gemm_pass(A, Wh, Wl, rowBase, lr, lk, acc);
    if (DUAL) gemm_pass(A2, Wh2, Wl2, rowBase, lr, lk, acc);

    // epilogue: C/D layout col=lane&15, row=(lane>>4)*4+reg  [verified mapping]
#pragma unroll
    for (int mt = 0; mt < 2; ++mt) {
#pragma unroll
        for (int nt = 0; nt < 8; ++nt) {
            int col = nt * 16 + lr;
            float b = bias[col];
#pragma unroll
            for (int r = 0; r < 4; ++r) {
                int row = rowBase + mt * 16 + lk * 4 + r;
                if (row < NN) {
                    float v = acc[mt][nt][r] + b;
                    out[(size_t)row * 128 + col] = v > 0.f ? v : 0.f;
                }
            }
        }
    }
}

// ---------------- mean aggregation over CSR: wave per node ----------------
__global__ __launch_bounds__(256) void k_agg(const float* __restrict__ h,
                                             const int* __restrict__ rp,
                                             const int* __restrict__ ssrc,
                                             float* __restrict__ out) {
    int wid = (int)((blockIdx.x * 256 + threadIdx.x) >> 6);
    int lane = threadIdx.x & 63;
    if (wid >= NN) return;
    int s = __builtin_amdgcn_readfirstlane(rp[wid]);
    int e = __builtin_amdgcn_readfirstlane(rp[wid + 1]);
    const float2* hp = (const float2*)h;
    float ax = 0.f, ay = 0.f;
    int i = s;
    for (; i + 4 <= e; i += 4) {
        int s0 = ssrc[i], s1 = ssrc[i + 1], s2 = ssrc[i + 2], s3 = ssrc[i + 3];
        float2 v0 = hp[(size_t)s0 * 64 + lane];
        float2 v1 = hp[(size_t)s1 * 64 + lane];
        float2 v2 = hp[(size_t)s2 * 64 + lane];
        float2 v3 = hp[(size_t)s3 * 64 + lane];
        ax += v0.x + v1.x + v2.x + v3.x;
        ay += v0.y + v1.y + v2.y + v3.y;
    }
    for (; i < e; ++i) {
        int s0 = ssrc[i];
        float2 v0 = hp[(size_t)s0 * 64 + lane];
        ax += v0.x;
        ay += v0.y;
    }
    int deg = e - s;
    float inv = deg > 0 ? 1.0f / (float)deg : 0.f;
    float2 o;
    o.x = ax * inv;
    o.y = ay * inv;
    ((float2*)out)[(size_t)wid * 64 + lane] = o;
}

// ---------------- launch ----------------
extern "C" void kernel_launch(void* const* d_in, const int* in_sizes, int n_in,
                              void* d_out, int out_size, void* d_ws, size_t ws_size,
                              hipStream_t stream) {
    const float* x = (const float*)d_in[0];
    const int* ei32 = (const int*)d_in[1];
    const long long* ei64 = (const long long*)d_in[1];
    const float* b1 = (const float*)d_in[3];
    const float* b2 = (const float*)d_in[5];
    const float* c1_bl = (const float*)d_in[7];
    const float* c2_bl = (const float*)d_in[10];
    float* out = (float*)d_out;

    char* ws = (char*)d_ws;
    const size_t HBYTES = (size_t)NN * 128 * 4;  // 51,200,000
    float* hA = (float*)ws;
    float* agg = (float*)(ws + HBYTES);
    int* ssrc = (int*)(ws + 2 * HBYTES);                    // E ints
    int* rp = (int*)(ws + 2 * HBYTES + 6400000);            // N+1 ints (padded 400128)
    int* bufs = (int*)(ws + 2 * HBYTES + 6400000 + 400128); // small bucket arrays
    short* whi = (short*)(ws + 2 * HBYTES + 6400000 + 2 * 400128);
    short* wlo = whi + 6 * 16384;
    int* flag = (int*)((char*)(wlo + 6 * 16384));

    int* bcnt = bufs;                // NBUK
    int* bbase = bufs + 256;         // NBUK+1
    int* bcur = bufs + 512;          // NBUK
    unsigned* eb = (unsigned*)hA;    // E staged edges (hA written only later)

    k_detect<<<1, 256, 0, stream>>>(ei64, flag);
    hipMemsetAsync(bcnt, 0, NBUK * 4, stream);
    int pgrid = (EE + EPB - 1) / EPB;   // 196
    k_bhist<<<pgrid, 1024, 0, stream>>>(ei32, ei64, flag, bcnt);
    k_bscan<<<1, 256, 0, stream>>>(bcnt, bbase, bcur);
    k_part<<<pgrid, 1024, 0, stream>>>(ei32, ei64, flag, bcur, eb);
    k_bucket<<<NBUK, 1024, 0, stream>>>(eb, bbase, rp, ssrc);
    k_prepw<<<(6 * 16384 + 255) / 256, 256, 0, stream>>>(
        (const float*)d_in[2], (const float*)d_in[6], (const float*)d_in[8],
        (const float*)d_in[4], (const float*)d_in[9], (const float*)d_in[11], whi, wlo);

    dim3 g((NN + 127) / 128);
    int agrid = (NN + 3) / 4;
    // h1 = relu(x@W1.T+b1)
    k_gemm<false><<<g, 256, 0, stream>>>(x, whi + 0 * 16384, wlo + 0 * 16384,
                                         nullptr, nullptr, nullptr, b1, hA);
    // conv1
    k_agg<<<agrid, 256, 0, stream>>>(hA, rp, ssrc, agg);
    k_gemm<true><<<g, 256, 0, stream>>>(agg, whi + 1 * 16384, wlo + 1 * 16384,
                                        hA, whi + 2 * 16384, wlo + 2 * 16384, c1_bl, out);
    // h3 = relu(h2@W2.T+b2)
    k_gemm<false><<<g, 256, 0, stream>>>(out, whi + 3 * 16384, wlo + 3 * 16384,
                                         nullptr, nullptr, nullptr, b2, hA);
    // conv2
    k_agg<<<agrid, 256, 0, stream>>>(hA, rp, ssrc, agg);
    k_gemm<true><<<g, 256, 0, stream>>>(agg, whi + 4 * 16384, wlo + 4 * 16384,
                                        hA, whi + 5 * 16384, wlo + 5 * 16384, c2_bl, out);
}

// Round 4
// 521.031 us; speedup vs baseline: 2.0224x; 1.2480x over previous
//
#include <hip/hip_runtime.h>
#include <hip/hip_bf16.h>

#define NN 100000
#define EE 1600000
#define DD 128

#define BSH 9                       // 512 nodes per bucket
#define NBUK ((NN + 511) / 512)     // 196
#define EPB 8192                    // edges per block in partition kernels

typedef __attribute__((ext_vector_type(8))) _Float16 half8;
typedef __attribute__((ext_vector_type(2))) _Float16 half2v;
typedef __attribute__((ext_vector_type(4))) float f32x4;

// ---------------- dtype detection (int32 vs int64 edge_index) ----------------
__global__ void k_detect(const long long* __restrict__ ei64, int* __restrict__ flag) {
    __shared__ int ok;
    if (threadIdx.x == 0) ok = 1;
    __syncthreads();
    long long v = ei64[threadIdx.x];   // 256 samples; safe either way (2E elems)
    if (v < 0 || v >= (long long)NN) atomicAnd(&ok, 0);
    __syncthreads();
    if (threadIdx.x == 0) *flag = ok;  // 1 => int64 layout, 0 => int32
}

__device__ inline int load_edge(const int* ei32, const long long* ei64, int is64, size_t pos) {
    return is64 ? (int)ei64[pos] : ei32[pos];
}

// ---------------- bucket histogram (196 buckets of 512 dst nodes) ----------------
__global__ __launch_bounds__(1024) void k_bhist(const int* __restrict__ ei32,
                                                const long long* __restrict__ ei64,
                                                const int* __restrict__ flag,
                                                int* __restrict__ bcnt) {
    __shared__ int h[NBUK];
    int t = threadIdx.x;
    if (t < NBUK) h[t] = 0;
    __syncthreads();
    int is64 = *flag;
    int base = blockIdx.x * EPB;
    int end = min(base + EPB, EE);
    for (int e = base + t; e < end; e += 1024) {
        int d = load_edge(ei32, ei64, is64, (size_t)EE + e);
        atomicAdd(&h[d >> BSH], 1);
    }
    __syncthreads();
    if (t < NBUK && h[t] > 0) atomicAdd(&bcnt[t], h[t]);
}

__global__ __launch_bounds__(256) void k_bscan(const int* __restrict__ bcnt,
                                               int* __restrict__ bbase,
                                               int* __restrict__ bcur) {
    __shared__ int sm[256];
    int t = threadIdx.x;
    int v = (t < NBUK) ? bcnt[t] : 0;
    sm[t] = v;
    __syncthreads();
    for (int off = 1; off < 256; off <<= 1) {
        int u = (t >= off) ? sm[t - off] : 0;
        __syncthreads();
        sm[t] += u;
        __syncthreads();
    }
    if (t < NBUK) {
        int b = sm[t] - v;
        bbase[t] = b;
        bcur[t] = b;
    }
    if (t == 0) bbase[NBUK] = EE;
}

// ---------------- partition edges into bucket-contiguous staging ----------------
// staged value: src (17 bits) | dstLocal (9 bits) << 17
__global__ __launch_bounds__(1024) void k_part(const int* __restrict__ ei32,
                                               const long long* __restrict__ ei64,
                                               const int* __restrict__ flag,
                                               int* __restrict__ bcur,
                                               unsigned* __restrict__ eb) {
    __shared__ int h[NBUK];
    __shared__ int cbase[NBUK];
    int t = threadIdx.x;
    if (t < NBUK) h[t] = 0;
    __syncthreads();
    int is64 = *flag;
    int base = blockIdx.x * EPB;
    int end = min(base + EPB, EE);
    int mys[8], myd[8];
    int cnt_i = 0;
    for (int e = base + t; e < end; e += 1024) {
        int s = load_edge(ei32, ei64, is64, (size_t)e);
        int d = load_edge(ei32, ei64, is64, (size_t)EE + e);
        mys[cnt_i] = s;
        myd[cnt_i] = d;
        ++cnt_i;
        atomicAdd(&h[d >> BSH], 1);
    }
    __syncthreads();
    if (t < NBUK && h[t] > 0) cbase[t] = atomicAdd(&bcur[t], h[t]);
    __syncthreads();
    if (t < NBUK) h[t] = 0;   // reuse as local cursor
    __syncthreads();
    for (int i = 0; i < cnt_i; ++i) {
        int b = myd[i] >> BSH;
        int slot = atomicAdd(&h[b], 1);
        unsigned v = (unsigned)mys[i] | ((unsigned)(myd[i] & 511) << 17);
        eb[cbase[b] + slot] = v;
    }
}

// ---------------- per-bucket counting sort: one block per bucket ----------------
__global__ __launch_bounds__(1024) void k_bucket(const unsigned* __restrict__ eb,
                                                 const int* __restrict__ bbase,
                                                 int* __restrict__ rp,
                                                 int* __restrict__ ssrc) {
    __shared__ int ncnt[512];
    __shared__ int cur[512];
    int b = blockIdx.x, t = threadIdx.x;
    int ebeg = bbase[b], eend = bbase[b + 1];
    int nodeBase = b << BSH;
    int nNodes = min(512, NN - nodeBase);
    if (t < 512) ncnt[t] = 0;
    __syncthreads();
    for (int i = ebeg + t; i < eend; i += 1024) {
        unsigned v = eb[i];
        atomicAdd(&ncnt[v >> 17], 1);
    }
    __syncthreads();
    int own = (t < 512) ? ncnt[t] : 0;
    for (int off = 1; off < 512; off <<= 1) {
        int u = (t >= off && t < 512) ? ncnt[t - off] : 0;
        __syncthreads();
        if (t < 512) ncnt[t] += u;
        __syncthreads();
    }
    if (t < 512) {
        int excl = ncnt[t] - own;
        cur[t] = ebeg + excl;
        if (t < nNodes) rp[nodeBase + t] = ebeg + excl;
    }
    __syncthreads();
    for (int i = ebeg + t; i < eend; i += 1024) {
        unsigned v = eb[i];
        int slot = atomicAdd(&cur[v >> 17], 1);
        ssrc[slot] = (int)(v & 0x1FFFFu);
    }
    if (b == 0 && t == 0) rp[NN] = EE;
}

// ---------------- weight split: f32 -> f16 hi + f16 lo (error ~2^-22) ----------------
__global__ void k_prepw(const float* __restrict__ w0, const float* __restrict__ w1,
                        const float* __restrict__ w2, const float* __restrict__ w3,
                        const float* __restrict__ w4, const float* __restrict__ w5,
                        _Float16* __restrict__ whi, _Float16* __restrict__ wlo) {
    int i = blockIdx.x * 256 + threadIdx.x;     // 6 * 16384
    if (i >= 6 * 16384) return;
    int slot = i >> 14, idx = i & 16383;
    const float* w = slot == 0 ? w0 : slot == 1 ? w1 : slot == 2 ? w2
                   : slot == 3 ? w3 : slot == 4 ? w4 : w5;
    float x = w[idx];
    _Float16 h = (_Float16)x;
    _Float16 l = (_Float16)(x - (float)h);
    whi[i] = h;
    wlo[i] = l;
}

// ---------------- GEMM: out = relu(A@Wa.T [+ A2@Wb.T] + bias) ----------------
// A row-major [N,128] f32 or fp16; W split into fp16 hi/lo row-major [128,128].
// fp16 A: exact, 2 MFMAs/tile. f32 A: f16 hi/lo split, 3 MFMAs/tile (err ~2^-22).
template <bool AF16>
__device__ inline void gemm_pass(const void* __restrict__ Av,
                                 const _Float16* __restrict__ Wh,
                                 const _Float16* __restrict__ Wl,
                                 int rowBase, int lr, int lk, f32x4 acc[2][8]) {
#pragma unroll
    for (int ks = 0; ks < 4; ++ks) {
        int kf = ks * 32 + lk * 8;
        half8 bh[8], bl[8];
#pragma unroll
        for (int nt = 0; nt < 8; ++nt) {
            int n = nt * 16 + lr;
            bh[nt] = *(const half8*)(Wh + n * 128 + kf);
            bl[nt] = *(const half8*)(Wl + n * 128 + kf);
        }
#pragma unroll
        for (int mt = 0; mt < 2; ++mt) {
            int row = rowBase + mt * 16 + lr;
            int rc = row < NN ? row : NN - 1;
            half8 ah, al;
            if (AF16) {
                ah = *(const half8*)((const _Float16*)Av + (size_t)rc * 128 + kf);
            } else {
                const float* ap = (const float*)Av + (size_t)rc * 128 + kf;
                float4 a0 = *(const float4*)ap;
                float4 a1 = *(const float4*)(ap + 4);
                float av[8] = {a0.x, a0.y, a0.z, a0.w, a1.x, a1.y, a1.z, a1.w};
#pragma unroll
                for (int j = 0; j < 8; ++j) {
                    _Float16 h = (_Float16)av[j];
                    ah[j] = h;
                    al[j] = (_Float16)(av[j] - (float)h);
                }
            }
#pragma unroll
            for (int nt = 0; nt < 8; ++nt) {
                acc[mt][nt] = __builtin_amdgcn_mfma_f32_16x16x32_f16(ah, bh[nt], acc[mt][nt], 0, 0, 0);
                acc[mt][nt] = __builtin_amdgcn_mfma_f32_16x16x32_f16(ah, bl[nt], acc[mt][nt], 0, 0, 0);
                if (!AF16)
                    acc[mt][nt] = __builtin_amdgcn_mfma_f32_16x16x32_f16(al, bh[nt], acc[mt][nt], 0, 0, 0);
            }
        }
    }
}

template <bool DUAL, bool AF16, bool OF16>
__global__ __launch_bounds__(256) void k_gemm(const void* __restrict__ A,
                                              const _Float16* __restrict__ Wh,
                                              const _Float16* __restrict__ Wl,
                                              const void* __restrict__ A2,
                                              const _Float16* __restrict__ Wh2,
                                              const _Float16* __restrict__ Wl2,
                                              const float* __restrict__ bias,
                                              void* __restrict__ out) {
    int wave = threadIdx.x >> 6;
    int lane = threadIdx.x & 63;
    int lr = lane & 15;
    int lk = lane >> 4;
    int rowBase = blockIdx.x * 128 + wave * 32;

    f32x4 acc[2][8];
#pragma unroll
    for (int mt = 0; mt < 2; ++mt)
#pragma unroll
        for (int nt = 0; nt < 8; ++nt) acc[mt][nt] = (f32x4){0.f, 0.f, 0.f, 0.f};

    gemm_pass<AF16>(A, Wh, Wl, rowBase, lr, lk, acc);
    if (DUAL) gemm_pass<AF16>(A2, Wh2, Wl2, rowBase, lr, lk, acc);

    // epilogue: C/D layout col=lane&15, row=(lane>>4)*4+reg  [verified mapping]
#pragma unroll
    for (int mt = 0; mt < 2; ++mt) {
#pragma unroll
        for (int nt = 0; nt < 8; ++nt) {
            int col = nt * 16 + lr;
            float b = bias[col];
#pragma unroll
            for (int r = 0; r < 4; ++r) {
                int row = rowBase + mt * 16 + lk * 4 + r;
                if (row < NN) {
                    float v = acc[mt][nt][r] + b;
                    v = v > 0.f ? v : 0.f;
                    if (OF16)
                        ((_Float16*)out)[(size_t)row * 128 + col] = (_Float16)v;
                    else
                        ((float*)out)[(size_t)row * 128 + col] = v;
                }
            }
        }
    }
}

// ---------------- mean aggregation over CSR: wave per node, fp16 table ----------------
__global__ __launch_bounds__(256) void k_agg(const _Float16* __restrict__ h,
                                             const int* __restrict__ rp,
                                             const int* __restrict__ ssrc,
                                             _Float16* __restrict__ out) {
    int wid = (int)((blockIdx.x * 256 + threadIdx.x) >> 6);
    int lane = threadIdx.x & 63;
    if (wid >= NN) return;
    int s = __builtin_amdgcn_readfirstlane(rp[wid]);
    int e = __builtin_amdgcn_readfirstlane(rp[wid + 1]);
    const half2v* hp = (const half2v*)h;
    float ax = 0.f, ay = 0.f;
    int i = s;
    for (; i + 4 <= e; i += 4) {
        int s0 = ssrc[i], s1 = ssrc[i + 1], s2 = ssrc[i + 2], s3 = ssrc[i + 3];
        half2v v0 = hp[(size_t)s0 * 64 + lane];
        half2v v1 = hp[(size_t)s1 * 64 + lane];
        half2v v2 = hp[(size_t)s2 * 64 + lane];
        half2v v3 = hp[(size_t)s3 * 64 + lane];
        ax += (float)v0.x + (float)v1.x + (float)v2.x + (float)v3.x;
        ay += (float)v0.y + (float)v1.y + (float)v2.y + (float)v3.y;
    }
    for (; i < e; ++i) {
        int s0 = ssrc[i];
        half2v v0 = hp[(size_t)s0 * 64 + lane];
        ax += (float)v0.x;
        ay += (float)v0.y;
    }
    int deg = e - s;
    float inv = deg > 0 ? 1.0f / (float)deg : 0.f;
    half2v o;
    o.x = (_Float16)(ax * inv);
    o.y = (_Float16)(ay * inv);
    ((half2v*)out)[(size_t)wid * 64 + lane] = o;
}

// ---------------- launch ----------------
extern "C" void kernel_launch(void* const* d_in, const int* in_sizes, int n_in,
                              void* d_out, int out_size, void* d_ws, size_t ws_size,
                              hipStream_t stream) {
    const float* x = (const float*)d_in[0];
    const int* ei32 = (const int*)d_in[1];
    const long long* ei64 = (const long long*)d_in[1];
    const float* b1 = (const float*)d_in[3];
    const float* b2 = (const float*)d_in[5];
    const float* c1_bl = (const float*)d_in[7];
    const float* c2_bl = (const float*)d_in[10];

    char* ws = (char*)d_ws;
    const size_t H16 = (size_t)NN * 128 * 2;     // 25,600,000
    _Float16* hH = (_Float16*)ws;                // fp16 node table
    _Float16* aggH = (_Float16*)(ws + H16);      // fp16 mean table
    int* ssrc = (int*)(ws + 2 * H16);            // E ints
    int* rp = (int*)(ws + 2 * H16 + 6400000);    // N+1 (padded 400128)
    int* bufs = (int*)(ws + 2 * H16 + 6400000 + 400128);
    _Float16* whi = (_Float16*)(ws + 2 * H16 + 6400000 + 2 * 400128);
    _Float16* wlo = whi + 6 * 16384;
    int* flag = (int*)((char*)(wlo + 6 * 16384));

    int* bcnt = bufs;                // NBUK
    int* bbase = bufs + 256;         // NBUK+1
    int* bcur = bufs + 512;          // NBUK
    unsigned* eb = (unsigned*)hH;    // E staged edges (hH written only later)

    k_detect<<<1, 256, 0, stream>>>(ei64, flag);
    hipMemsetAsync(bcnt, 0, NBUK * 4, stream);
    int pgrid = (EE + EPB - 1) / EPB;   // 196
    k_bhist<<<pgrid, 1024, 0, stream>>>(ei32, ei64, flag, bcnt);
    k_bscan<<<1, 256, 0, stream>>>(bcnt, bbase, bcur);
    k_part<<<pgrid, 1024, 0, stream>>>(ei32, ei64, flag, bcur, eb);
    k_bucket<<<NBUK, 1024, 0, stream>>>(eb, bbase, rp, ssrc);
    k_prepw<<<(6 * 16384 + 255) / 256, 256, 0, stream>>>(
        (const float*)d_in[2], (const float*)d_in[6], (const float*)d_in[8],
        (const float*)d_in[4], (const float*)d_in[9], (const float*)d_in[11], whi, wlo);

    dim3 g((NN + 127) / 128);
    int agrid = (NN + 3) / 4;
    // h1 = relu(x@W1.T+b1) -> fp16
    k_gemm<false, false, true><<<g, 256, 0, stream>>>(
        x, whi + 0 * 16384, wlo + 0 * 16384, nullptr, nullptr, nullptr, b1, hH);
    // conv1: mean-agg (fp16) then dual GEMM -> f32 d_out
    k_agg<<<agrid, 256, 0, stream>>>(hH, rp, ssrc, aggH);
    k_gemm<true, true, false><<<g, 256, 0, stream>>>(
        aggH, whi + 1 * 16384, wlo + 1 * 16384,
        hH, whi + 2 * 16384, wlo + 2 * 16384, c1_bl, d_out);
    // h3 = relu(h2@W2.T+b2) -> fp16
    k_gemm<false, false, true><<<g, 256, 0, stream>>>(
        d_out, whi + 3 * 16384, wlo + 3 * 16384, nullptr, nullptr, nullptr, b2, hH);
    // conv2
    k_agg<<<agrid, 256, 0, stream>>>(hH, rp, ssrc, aggH);
    k_gemm<true, true, false><<<g, 256, 0, stream>>>(
        aggH, whi + 4 * 16384, wlo + 4 * 16384,
        hH, whi + 5 * 16384, wlo + 5 * 16384, c2_bl, d_out);
}

// Round 5
// 396.574 us; speedup vs baseline: 2.6570x; 1.3138x over previous
//
#include <hip/hip_runtime.h>
#include <hip/hip_bf16.h>

#define NN 100000
#define EE 1600000
#define DD 128

#define BSH 9                       // 512 nodes per bucket
#define NBUK ((NN + 511) / 512)     // 196
#define EPB 8192                    // edges per block in partition kernels

typedef __attribute__((ext_vector_type(8))) _Float16 half8;
typedef __attribute__((ext_vector_type(2))) _Float16 half2v;
typedef __attribute__((ext_vector_type(4))) float f32x4;

// ---------------- dtype detection (int32 vs int64 edge_index) ----------------
__global__ void k_detect(const long long* __restrict__ ei64, int* __restrict__ flag) {
    __shared__ int ok;
    if (threadIdx.x == 0) ok = 1;
    __syncthreads();
    long long v = ei64[threadIdx.x];   // 256 samples; safe either way (2E elems)
    if (v < 0 || v >= (long long)NN) atomicAnd(&ok, 0);
    __syncthreads();
    if (threadIdx.x == 0) *flag = ok;  // 1 => int64 layout, 0 => int32
}

__device__ inline int load_edge(const int* ei32, const long long* ei64, int is64, size_t pos) {
    return is64 ? (int)ei64[pos] : ei32[pos];
}

// ---------------- bucket histogram (196 buckets of 512 dst nodes) ----------------
__global__ __launch_bounds__(1024) void k_bhist(const int* __restrict__ ei32,
                                                const long long* __restrict__ ei64,
                                                const int* __restrict__ flag,
                                                int* __restrict__ bcnt) {
    __shared__ int h[NBUK];
    int t = threadIdx.x;
    if (t < NBUK) h[t] = 0;
    __syncthreads();
    int is64 = *flag;
    int base = blockIdx.x * EPB;
    int end = min(base + EPB, EE);
    for (int e = base + t; e < end; e += 1024) {
        int d = load_edge(ei32, ei64, is64, (size_t)EE + e);
        atomicAdd(&h[d >> BSH], 1);
    }
    __syncthreads();
    if (t < NBUK && h[t] > 0) atomicAdd(&bcnt[t], h[t]);
}

__global__ __launch_bounds__(256) void k_bscan(const int* __restrict__ bcnt,
                                               int* __restrict__ bbase,
                                               int* __restrict__ bcur) {
    __shared__ int sm[256];
    int t = threadIdx.x;
    int v = (t < NBUK) ? bcnt[t] : 0;
    sm[t] = v;
    __syncthreads();
    for (int off = 1; off < 256; off <<= 1) {
        int u = (t >= off) ? sm[t - off] : 0;
        __syncthreads();
        sm[t] += u;
        __syncthreads();
    }
    if (t < NBUK) {
        int b = sm[t] - v;
        bbase[t] = b;
        bcur[t] = b;
    }
    if (t == 0) bbase[NBUK] = EE;
}

// ---------------- partition edges into bucket-contiguous staging ----------------
// staged value: src (17 bits) | dstLocal (9 bits) << 17
__global__ __launch_bounds__(1024) void k_part(const int* __restrict__ ei32,
                                               const long long* __restrict__ ei64,
                                               const int* __restrict__ flag,
                                               int* __restrict__ bcur,
                                               unsigned* __restrict__ eb) {
    __shared__ int h[NBUK];
    __shared__ int cbase[NBUK];
    int t = threadIdx.x;
    if (t < NBUK) h[t] = 0;
    __syncthreads();
    int is64 = *flag;
    int base = blockIdx.x * EPB;
    int end = min(base + EPB, EE);
    int mys[8], myd[8];
    int cnt_i = 0;
    for (int e = base + t; e < end; e += 1024) {
        int s = load_edge(ei32, ei64, is64, (size_t)e);
        int d = load_edge(ei32, ei64, is64, (size_t)EE + e);
        mys[cnt_i] = s;
        myd[cnt_i] = d;
        ++cnt_i;
        atomicAdd(&h[d >> BSH], 1);
    }
    __syncthreads();
    if (t < NBUK && h[t] > 0) cbase[t] = atomicAdd(&bcur[t], h[t]);
    __syncthreads();
    if (t < NBUK) h[t] = 0;   // reuse as local cursor
    __syncthreads();
    for (int i = 0; i < cnt_i; ++i) {
        int b = myd[i] >> BSH;
        int slot = atomicAdd(&h[b], 1);
        unsigned v = (unsigned)mys[i] | ((unsigned)(myd[i] & 511) << 17);
        eb[cbase[b] + slot] = v;
    }
}

// ---------------- per-bucket counting sort: one block per bucket ----------------
__global__ __launch_bounds__(1024) void k_bucket(const unsigned* __restrict__ eb,
                                                 const int* __restrict__ bbase,
                                                 int* __restrict__ rp,
                                                 int* __restrict__ ssrc) {
    __shared__ int ncnt[512];
    __shared__ int cur[512];
    int b = blockIdx.x, t = threadIdx.x;
    int ebeg = bbase[b], eend = bbase[b + 1];
    int nodeBase = b << BSH;
    int nNodes = min(512, NN - nodeBase);
    if (t < 512) ncnt[t] = 0;
    __syncthreads();
    for (int i = ebeg + t; i < eend; i += 1024) {
        unsigned v = eb[i];
        atomicAdd(&ncnt[v >> 17], 1);
    }
    __syncthreads();
    int own = (t < 512) ? ncnt[t] : 0;
    for (int off = 1; off < 512; off <<= 1) {
        int u = (t >= off && t < 512) ? ncnt[t - off] : 0;
        __syncthreads();
        if (t < 512) ncnt[t] += u;
        __syncthreads();
    }
    if (t < 512) {
        int excl = ncnt[t] - own;
        cur[t] = ebeg + excl;
        if (t < nNodes) rp[nodeBase + t] = ebeg + excl;
    }
    __syncthreads();
    for (int i = ebeg + t; i < eend; i += 1024) {
        unsigned v = eb[i];
        int slot = atomicAdd(&cur[v >> 17], 1);
        ssrc[slot] = (int)(v & 0x1FFFFu);
    }
    if (b == 0 && t == 0) rp[NN] = EE;
}

// ---------------- weight prep: f32 -> fp16 (single precision level) ----------------
__global__ void k_prepw(const float* __restrict__ w0, const float* __restrict__ w1,
                        const float* __restrict__ w2, const float* __restrict__ w3,
                        const float* __restrict__ w4, const float* __restrict__ w5,
                        _Float16* __restrict__ whi) {
    int i = blockIdx.x * 256 + threadIdx.x;     // 6 * 16384
    if (i >= 6 * 16384) return;
    int slot = i >> 14, idx = i & 16383;
    const float* w = slot == 0 ? w0 : slot == 1 ? w1 : slot == 2 ? w2
                   : slot == 3 ? w3 : slot == 4 ? w4 : w5;
    whi[i] = (_Float16)w[idx];
}

// ---------------- GEMM: out = relu(A@W1.T [+ A2@W2.T] + bias) ----------------
// W staged in LDS (row stride 136 fp16 = 272B: 16B-aligned b128 reads, 2-way banks).
// fp16 A: 1 MFMA/tile. f32 A: f16 hi/lo split of A, 2 MFMAs/tile.
#define WSTR 136

template <bool DUAL, bool AF16, bool OF16>
__global__ __launch_bounds__(256) void k_gemm(const void* __restrict__ A,
                                              const _Float16* __restrict__ W1g,
                                              const void* __restrict__ A2,
                                              const _Float16* __restrict__ W2g,
                                              const float* __restrict__ bias,
                                              void* __restrict__ out) {
    __shared__ _Float16 sW[128 * WSTR];
    int t = threadIdx.x;
    int wave = t >> 6;
    int lane = t & 63;
    int lr = lane & 15;
    int lk = lane >> 4;
    int rowBase = blockIdx.x * 128 + wave * 32;

    f32x4 acc[2][8];
#pragma unroll
    for (int mt = 0; mt < 2; ++mt)
#pragma unroll
        for (int nt = 0; nt < 8; ++nt) acc[mt][nt] = (f32x4){0.f, 0.f, 0.f, 0.f};

    const int NPASS = DUAL ? 2 : 1;
    for (int pass = 0; pass < NPASS; ++pass) {
        const _Float16* Wg = pass ? W2g : W1g;
        const void* Ap = pass ? A2 : A;
        if (pass) __syncthreads();             // protect LDS before overwrite
        // stage weights: 2048 16B chunks, 8 per thread, coalesced
#pragma unroll
        for (int i = 0; i < 8; ++i) {
            int c = t + i * 256;
            int n = c >> 4, j = c & 15;
            *(half8*)(sW + n * WSTR + j * 8) = *(const half8*)(Wg + n * 128 + j * 8);
        }
        __syncthreads();

#pragma unroll
        for (int ks = 0; ks < 4; ++ks) {
            int kf = ks * 32 + lk * 8;
            half8 b[8];
#pragma unroll
            for (int nt = 0; nt < 8; ++nt)
                b[nt] = *(const half8*)(sW + (nt * 16 + lr) * WSTR + (ks * 4 + lk) * 8);
#pragma unroll
            for (int mt = 0; mt < 2; ++mt) {
                int row = rowBase + mt * 16 + lr;
                int rc = row < NN ? row : NN - 1;
                if (AF16) {
                    half8 a = *(const half8*)((const _Float16*)Ap + (size_t)rc * 128 + kf);
#pragma unroll
                    for (int nt = 0; nt < 8; ++nt)
                        acc[mt][nt] = __builtin_amdgcn_mfma_f32_16x16x32_f16(a, b[nt], acc[mt][nt], 0, 0, 0);
                } else {
                    const float* ap = (const float*)Ap + (size_t)rc * 128 + kf;
                    float4 a0 = *(const float4*)ap;
                    float4 a1 = *(const float4*)(ap + 4);
                    float av[8] = {a0.x, a0.y, a0.z, a0.w, a1.x, a1.y, a1.z, a1.w};
                    half8 ah, al;
#pragma unroll
                    for (int j = 0; j < 8; ++j) {
                        _Float16 h = (_Float16)av[j];
                        ah[j] = h;
                        al[j] = (_Float16)(av[j] - (float)h);
                    }
#pragma unroll
                    for (int nt = 0; nt < 8; ++nt) {
                        acc[mt][nt] = __builtin_amdgcn_mfma_f32_16x16x32_f16(ah, b[nt], acc[mt][nt], 0, 0, 0);
                        acc[mt][nt] = __builtin_amdgcn_mfma_f32_16x16x32_f16(al, b[nt], acc[mt][nt], 0, 0, 0);
                    }
                }
            }
        }
    }

    // epilogue: C/D layout col=lane&15, row=(lane>>4)*4+reg  [verified mapping]
#pragma unroll
    for (int mt = 0; mt < 2; ++mt) {
#pragma unroll
        for (int nt = 0; nt < 8; ++nt) {
            int col = nt * 16 + lr;
            float b = bias[col];
#pragma unroll
            for (int r = 0; r < 4; ++r) {
                int row = rowBase + mt * 16 + lk * 4 + r;
                if (row < NN) {
                    float v = acc[mt][nt][r] + b;
                    v = v > 0.f ? v : 0.f;
                    if (OF16)
                        ((_Float16*)out)[(size_t)row * 128 + col] = (_Float16)v;
                    else
                        ((float*)out)[(size_t)row * 128 + col] = v;
                }
            }
        }
    }
}

// ---------------- mean aggregation over CSR: wave per node, fp16 table ----------------
__global__ __launch_bounds__(256) void k_agg(const _Float16* __restrict__ h,
                                             const int* __restrict__ rp,
                                             const int* __restrict__ ssrc,
                                             _Float16* __restrict__ out) {
    int wid = (int)((blockIdx.x * 256 + threadIdx.x) >> 6);
    int lane = threadIdx.x & 63;
    if (wid >= NN) return;
    int s = __builtin_amdgcn_readfirstlane(rp[wid]);
    int e = __builtin_amdgcn_readfirstlane(rp[wid + 1]);
    const half2v* hp = (const half2v*)h;
    float ax = 0.f, ay = 0.f;
    int i = s;
    for (; i + 4 <= e; i += 4) {
        int s0 = ssrc[i], s1 = ssrc[i + 1], s2 = ssrc[i + 2], s3 = ssrc[i + 3];
        half2v v0 = hp[(size_t)s0 * 64 + lane];
        half2v v1 = hp[(size_t)s1 * 64 + lane];
        half2v v2 = hp[(size_t)s2 * 64 + lane];
        half2v v3 = hp[(size_t)s3 * 64 + lane];
        ax += (float)v0.x + (float)v1.x + (float)v2.x + (float)v3.x;
        ay += (float)v0.y + (float)v1.y + (float)v2.y + (float)v3.y;
    }
    for (; i < e; ++i) {
        int s0 = ssrc[i];
        half2v v0 = hp[(size_t)s0 * 64 + lane];
        ax += (float)v0.x;
        ay += (float)v0.y;
    }
    int deg = e - s;
    float inv = deg > 0 ? 1.0f / (float)deg : 0.f;
    half2v o;
    o.x = (_Float16)(ax * inv);
    o.y = (_Float16)(ay * inv);
    ((half2v*)out)[(size_t)wid * 64 + lane] = o;
}

// ---------------- launch ----------------
extern "C" void kernel_launch(void* const* d_in, const int* in_sizes, int n_in,
                              void* d_out, int out_size, void* d_ws, size_t ws_size,
                              hipStream_t stream) {
    const float* x = (const float*)d_in[0];
    const int* ei32 = (const int*)d_in[1];
    const long long* ei64 = (const long long*)d_in[1];
    const float* b1 = (const float*)d_in[3];
    const float* b2 = (const float*)d_in[5];
    const float* c1_bl = (const float*)d_in[7];
    const float* c2_bl = (const float*)d_in[10];

    char* ws = (char*)d_ws;
    const size_t H16 = (size_t)NN * 128 * 2;     // 25,600,000
    _Float16* hH = (_Float16*)ws;                // fp16 node table
    _Float16* aggH = (_Float16*)(ws + H16);      // fp16 mean / h2 table
    int* ssrc = (int*)(ws + 2 * H16);            // E ints
    int* rp = (int*)(ws + 2 * H16 + 6400000);    // N+1 (padded 400128)
    int* bufs = (int*)(ws + 2 * H16 + 6400000 + 400128);
    _Float16* whi = (_Float16*)(ws + 2 * H16 + 6400000 + 2 * 400128);
    int* flag = (int*)((char*)(whi + 6 * 16384));

    int* bcnt = bufs;                // NBUK
    int* bbase = bufs + 256;         // NBUK+1
    int* bcur = bufs + 512;          // NBUK
    unsigned* eb = (unsigned*)hH;    // E staged edges (hH written only later)

    k_detect<<<1, 256, 0, stream>>>(ei64, flag);
    hipMemsetAsync(bcnt, 0, NBUK * 4, stream);
    int pgrid = (EE + EPB - 1) / EPB;   // 196
    k_bhist<<<pgrid, 1024, 0, stream>>>(ei32, ei64, flag, bcnt);
    k_bscan<<<1, 256, 0, stream>>>(bcnt, bbase, bcur);
    k_part<<<pgrid, 1024, 0, stream>>>(ei32, ei64, flag, bcur, eb);
    k_bucket<<<NBUK, 1024, 0, stream>>>(eb, bbase, rp, ssrc);
    k_prepw<<<(6 * 16384 + 255) / 256, 256, 0, stream>>>(
        (const float*)d_in[2], (const float*)d_in[6], (const float*)d_in[8],
        (const float*)d_in[4], (const float*)d_in[9], (const float*)d_in[11], whi);

    dim3 g((NN + 127) / 128);
    int agrid = (NN + 3) / 4;
    // h1 = relu(x@W1.T+b1) -> fp16 hH
    k_gemm<false, false, true><<<g, 256, 0, stream>>>(
        x, whi + 0 * 16384, nullptr, nullptr, b1, hH);
    // conv1: mean-agg then dual GEMM, output fp16 in-place over aggH
    k_agg<<<agrid, 256, 0, stream>>>(hH, rp, ssrc, aggH);
    k_gemm<true, true, true><<<g, 256, 0, stream>>>(
        aggH, whi + 1 * 16384, hH, whi + 2 * 16384, c1_bl, aggH);
    // h3 = relu(h2@W2.T+b2) -> fp16 hH
    k_gemm<false, true, true><<<g, 256, 0, stream>>>(
        aggH, whi + 3 * 16384, nullptr, nullptr, b2, hH);
    // conv2
    k_agg<<<agrid, 256, 0, stream>>>(hH, rp, ssrc, aggH);
    k_gemm<true, true, false><<<g, 256, 0, stream>>>(
        aggH, whi + 4 * 16384, hH, whi + 5 * 16384, c2_bl, d_out);
}